// Round 2
// baseline (319.113 us; speedup 1.0000x reference)
//
#include <hip/hip_runtime.h>

typedef unsigned int u32;
typedef unsigned short u16;
typedef unsigned long long u64;

#define NTOK 4096
#define DDIM 512
#define NEXP 8
#define HDIM 1024

typedef __attribute__((ext_vector_type(8))) __bf16 bf16x8;
typedef __attribute__((ext_vector_type(4))) float f32x4;

__device__ __forceinline__ float b2f(u16 u) {
    union { u32 i; float f; } v; v.i = ((u32)u) << 16; return v.f;
}
__device__ __forceinline__ u16 f2b(float f) {
    u32 x = __builtin_bit_cast(u32, f);
    x += 0x7fffu + ((x >> 16) & 1u);
    return (u16)(x >> 16);
}

// MODE 0 = tensors are bf16 in memory; MODE 1 = tensors are f32 in memory.
template<int MODE>
__device__ __forceinline__ float ldf(const void* p, size_t i) {
    return MODE ? ((const float*)p)[i] : b2f(((const u16*)p)[i]);
}

// Load 16 consecutive elements (element index `elem`, multiple of 16) as 16 bf16
// packed into two uint4.
template<int MODE>
__device__ __forceinline__ void load16(const void* base, size_t elem, uint4& lo, uint4& hi) {
    if (MODE == 0) {
        const uint4* p = (const uint4*)((const u16*)base + elem);
        lo = p[0]; hi = p[1];
    } else {
        const float4* p = (const float4*)((const float*)base + elem);
        const float4 a = p[0], b = p[1], c = p[2], d = p[3];
        union { u16 t[16]; uint4 v[2]; } u;
        u.t[0] = f2b(a.x); u.t[1] = f2b(a.y); u.t[2]  = f2b(a.z); u.t[3]  = f2b(a.w);
        u.t[4] = f2b(b.x); u.t[5] = f2b(b.y); u.t[6]  = f2b(b.z); u.t[7]  = f2b(b.w);
        u.t[8] = f2b(c.x); u.t[9] = f2b(c.y); u.t[10] = f2b(c.z); u.t[11] = f2b(c.w);
        u.t[12] = f2b(d.x); u.t[13] = f2b(d.y); u.t[14] = f2b(d.z); u.t[15] = f2b(d.w);
        lo = u.v[0]; hi = u.v[1];
    }
}

// ---------------- K0: detect dtype + zero expert counts ----------------
// Even-indexed u16s of x: bf16 -> sane exponents (~100%); f32 low-halves -> ~17%.
__global__ void detect_kernel(const u16* __restrict__ x, u32* __restrict__ flag,
                              u32* __restrict__ counts) {
    const int lane = threadIdx.x & 63;
    const u16 v = x[lane * 2];
    const int ex = (v >> 7) & 0xFF;
    const bool ok = (ex >= 97 && ex <= 140);   // |val| in [2^-30, 2^14]
    const u64 m = __ballot(ok);
    if (threadIdx.x == 0) *flag = (__popcll(m) >= 32) ? 0u : 1u;
    if (threadIdx.x < NEXP) counts[threadIdx.x] = 0;
}

// ---------------- K1: router (one wave per token) ----------------
template<int MODE>
__global__ __launch_bounds__(256) void router_kernel(
    const u32* __restrict__ flag,
    const void* __restrict__ x, const void* __restrict__ rw, const void* __restrict__ rb,
    u32* __restrict__ counts, u16* __restrict__ list,
    u32* __restrict__ tok_e, u32* __restrict__ tok_pos, float* __restrict__ tok_w)
{
    if (*flag != (u32)MODE) return;
    const int tid = threadIdx.x;
    const int lane = tid & 63;
    const int t = blockIdx.x * 4 + (tid >> 6);

    float xf[8];
    if (MODE == 0) {
        const uint4 xv = ((const uint4*)((const u16*)x + (size_t)t * DDIM))[lane];
        const u16* xs = (const u16*)&xv;
#pragma unroll
        for (int i = 0; i < 8; i++) xf[i] = b2f(xs[i]);
    } else {
        const float4* p = (const float4*)((const float*)x + (size_t)t * DDIM + lane * 8);
        const float4 a = p[0], b = p[1];
        xf[0] = a.x; xf[1] = a.y; xf[2] = a.z; xf[3] = a.w;
        xf[4] = b.x; xf[5] = b.y; xf[6] = b.z; xf[7] = b.w;
    }

    float acc[NEXP];
#pragma unroll
    for (int e = 0; e < NEXP; e++) {
        float wf[8];
        if (MODE == 0) {
            const uint4 wv = ((const uint4*)((const u16*)rw + e * DDIM))[lane];
            const u16* wp = (const u16*)&wv;
#pragma unroll
            for (int i = 0; i < 8; i++) wf[i] = b2f(wp[i]);
        } else {
            const float4* p = (const float4*)((const float*)rw + e * DDIM + lane * 8);
            const float4 a = p[0], b = p[1];
            wf[0] = a.x; wf[1] = a.y; wf[2] = a.z; wf[3] = a.w;
            wf[4] = b.x; wf[5] = b.y; wf[6] = b.z; wf[7] = b.w;
        }
        float s = 0.f;
#pragma unroll
        for (int i = 0; i < 8; i++) s += xf[i] * wf[i];
        acc[e] = s;
    }
#pragma unroll
    for (int off = 32; off > 0; off >>= 1) {
#pragma unroll
        for (int e = 0; e < NEXP; e++) acc[e] += __shfl_xor(acc[e], off, 64);
    }
    if (lane == 0) {
#pragma unroll
        for (int e = 0; e < NEXP; e++) acc[e] += ldf<MODE>(rb, e);
        int e0 = 0;
#pragma unroll
        for (int e = 1; e < NEXP; e++) if (acc[e] > acc[e0]) e0 = e;
        int e1 = -1;
#pragma unroll
        for (int e = 0; e < NEXP; e++) {
            if (e == e0) continue;
            if (e1 < 0 || acc[e] > acc[e1]) e1 = e;
        }
        const float v0 = acc[e0], v1 = acc[e1];
        const float w1v = 1.f / (1.f + __expf(v0 - v1));
        const float w0v = 1.f - w1v;
        const u32 p0 = atomicAdd(&counts[e0], 1u);
        const u32 p1 = atomicAdd(&counts[e1], 1u);
        list[e0 * NTOK + p0] = (u16)t;
        list[e1 * NTOK + p1] = (u16)t;
        tok_e[t * 2] = (u32)e0;      tok_pos[t * 2] = p0;      tok_w[t * 2] = w0v;
        tok_e[t * 2 + 1] = (u32)e1;  tok_pos[t * 2 + 1] = p1;  tok_w[t * 2 + 1] = w1v;
    }
}

// ---------------- K2: exclusive prefix over 8 counts ----------------
__global__ void prefix_kernel(const u32* __restrict__ counts, u32* __restrict__ offsets) {
    if (threadIdx.x == 0) {
        u32 o = 0;
        for (int e = 0; e < NEXP; e++) { offsets[e] = o; o += counts[e]; }
    }
}

// ---------------- K3: gathered fc1 + SwiGLU (bf16 MFMA 16x16x32) ----------------
template<int MODE>
__global__ __launch_bounds__(256) void fc1_swiglu_kernel(
    const u32* __restrict__ flag,
    const void* __restrict__ x, const void* __restrict__ fc1_w, const void* __restrict__ fc1_b,
    const u32* __restrict__ counts, const u32* __restrict__ offsets,
    const u16* __restrict__ list, u16* __restrict__ a_packed)
{
    if (*flag != (u32)MODE) return;
    const int e = blockIdx.z;
    const int cnt = (int)counts[e];
    const int row0 = blockIdx.y * 64;
    if (row0 >= cnt) return;
    const int n0 = blockIdx.x * 64;

    __shared__ u16 As[64 * 64], B1s[64 * 64], B2s[64 * 64];

    const int tid = threadIdx.x;
    const int lr = tid >> 2;            // loader row 0..63
    const int lc = (tid & 3) * 16;      // loader col base (elements)
    int ar = row0 + lr; if (ar >= cnt) ar = cnt - 1;
    const int tok = (int)list[e * NTOK + ar];
    const size_t a_base  = (size_t)tok * DDIM;
    const size_t b1_base = ((size_t)e * 2 * HDIM + (size_t)(n0 + lr)) * DDIM;
    const size_t b2_base = ((size_t)e * 2 * HDIM + (size_t)(n0 + HDIM + lr)) * DDIM;

    const int sw = lr & 7;
    const int c0 = lc >> 3;
    u16* as0  = &As[lr * 64 + ((c0 ^ sw) << 3)];
    u16* as1  = &As[lr * 64 + (((c0 + 1) ^ sw) << 3)];
    u16* b1s0 = &B1s[lr * 64 + ((c0 ^ sw) << 3)];
    u16* b1s1 = &B1s[lr * 64 + (((c0 + 1) ^ sw) << 3)];
    u16* b2s0 = &B2s[lr * 64 + ((c0 ^ sw) << 3)];
    u16* b2s1 = &B2s[lr * 64 + (((c0 + 1) ^ sw) << 3)];

    const int wave = tid >> 6, lane = tid & 63;
    const int mm = lane & 15;
    const int qb = lane >> 4;
    const int msw = mm & 7;
    const u16* a_rd = &As[(wave * 16 + mm) * 64];

    f32x4 acc1[4] = {f32x4{0,0,0,0},f32x4{0,0,0,0},f32x4{0,0,0,0},f32x4{0,0,0,0}};
    f32x4 acc2[4] = {f32x4{0,0,0,0},f32x4{0,0,0,0},f32x4{0,0,0,0},f32x4{0,0,0,0}};

    for (int k0 = 0; k0 < DDIM; k0 += 64) {
        uint4 av0, av1, b10, b11, b20, b21;
        load16<MODE>(x,     a_base  + k0 + lc, av0, av1);
        load16<MODE>(fc1_w, b1_base + k0 + lc, b10, b11);
        load16<MODE>(fc1_w, b2_base + k0 + lc, b20, b21);
        __syncthreads();
        *(uint4*)as0  = av0; *(uint4*)as1  = av1;
        *(uint4*)b1s0 = b10; *(uint4*)b1s1 = b11;
        *(uint4*)b2s0 = b20; *(uint4*)b2s1 = b21;
        __syncthreads();
#pragma unroll
        for (int kk = 0; kk < 2; kk++) {
            const int q = kk * 4 + qb;
            const bf16x8 af = *(const bf16x8*)(a_rd + ((q ^ msw) << 3));
#pragma unroll
            for (int nt = 0; nt < 4; nt++) {
                const bf16x8 bf1 = *(const bf16x8*)(&B1s[(nt * 16 + mm) * 64 + ((q ^ msw) << 3)]);
                const bf16x8 bf2 = *(const bf16x8*)(&B2s[(nt * 16 + mm) * 64 + ((q ^ msw) << 3)]);
                acc1[nt] = __builtin_amdgcn_mfma_f32_16x16x32_bf16(af, bf1, acc1[nt], 0, 0, 0);
                acc2[nt] = __builtin_amdgcn_mfma_f32_16x16x32_bf16(af, bf2, acc2[nt], 0, 0, 0);
            }
        }
    }

    const u32 obase = offsets[e];
    const int rbv = (lane >> 4) * 4;
#pragma unroll
    for (int nt = 0; nt < 4; nt++) {
        const int n = n0 + nt * 16 + mm;
        const float bb1 = ldf<MODE>(fc1_b, (size_t)e * 2 * HDIM + n);
        const float bb2 = ldf<MODE>(fc1_b, (size_t)e * 2 * HDIM + HDIM + n);
#pragma unroll
        for (int r = 0; r < 4; r++) {
            const int gr = row0 + wave * 16 + rbv + r;
            if (gr < cnt) {
                const float h1 = acc1[nt][r] + bb1;
                const float h2 = acc2[nt][r] + bb2;
                const float av = h1 / (1.f + __expf(-h1)) * h2;
                a_packed[(size_t)(obase + (u32)gr) * HDIM + n] = f2b(av);
            }
        }
    }
}

// ---------------- K4: fc2 on packed rows (bf16 MFMA) ----------------
template<int MODE>
__global__ __launch_bounds__(256) void fc2_kernel(
    const u32* __restrict__ flag,
    const u16* __restrict__ a_packed, const void* __restrict__ fc2_w, const void* __restrict__ fc2_b,
    const u32* __restrict__ counts, const u32* __restrict__ offsets,
    u16* __restrict__ y_packed)
{
    if (*flag != (u32)MODE) return;
    const int e = blockIdx.z;
    const int cnt = (int)counts[e];
    const int row0 = blockIdx.y * 64;
    if (row0 >= cnt) return;
    const int d0 = blockIdx.x * 64;

    __shared__ u16 As[64 * 64], Bs[64 * 64];

    const int tid = threadIdx.x;
    const int lr = tid >> 2;
    const int lc = (tid & 3) * 16;
    const u32 obase = offsets[e];
    int ar = row0 + lr; if (ar >= cnt) ar = cnt - 1;
    const size_t a_base = (size_t)(obase + (u32)ar) * HDIM;
    const size_t b_base = ((size_t)e * DDIM + (size_t)(d0 + lr)) * HDIM;

    const int sw = lr & 7;
    const int c0 = lc >> 3;
    u16* as0 = &As[lr * 64 + ((c0 ^ sw) << 3)];
    u16* as1 = &As[lr * 64 + (((c0 + 1) ^ sw) << 3)];
    u16* bs0 = &Bs[lr * 64 + ((c0 ^ sw) << 3)];
    u16* bs1 = &Bs[lr * 64 + (((c0 + 1) ^ sw) << 3)];

    const int wave = tid >> 6, lane = tid & 63;
    const int mm = lane & 15;
    const int qb = lane >> 4;
    const int msw = mm & 7;
    const u16* a_rd = &As[(wave * 16 + mm) * 64];

    f32x4 acc[4] = {f32x4{0,0,0,0},f32x4{0,0,0,0},f32x4{0,0,0,0},f32x4{0,0,0,0}};

    for (int k0 = 0; k0 < HDIM; k0 += 64) {
        uint4 av0, av1, bv0, bv1;
        load16<0>(a_packed, a_base + k0 + lc, av0, av1);       // a is always bf16
        load16<MODE>(fc2_w, b_base + k0 + lc, bv0, bv1);
        __syncthreads();
        *(uint4*)as0 = av0; *(uint4*)as1 = av1;
        *(uint4*)bs0 = bv0; *(uint4*)bs1 = bv1;
        __syncthreads();
#pragma unroll
        for (int kk = 0; kk < 2; kk++) {
            const int q = kk * 4 + qb;
            const bf16x8 af = *(const bf16x8*)(a_rd + ((q ^ msw) << 3));
#pragma unroll
            for (int nt = 0; nt < 4; nt++) {
                const bf16x8 bfv = *(const bf16x8*)(&Bs[(nt * 16 + mm) * 64 + ((q ^ msw) << 3)]);
                acc[nt] = __builtin_amdgcn_mfma_f32_16x16x32_bf16(af, bfv, acc[nt], 0, 0, 0);
            }
        }
    }

    const int rbv = (lane >> 4) * 4;
#pragma unroll
    for (int nt = 0; nt < 4; nt++) {
        const int n = d0 + nt * 16 + mm;
        const float bb = ldf<MODE>(fc2_b, (size_t)e * DDIM + n);
#pragma unroll
        for (int r = 0; r < 4; r++) {
            const int gr = row0 + wave * 16 + rbv + r;
            if (gr < cnt) {
                y_packed[(size_t)(obase + (u32)gr) * DDIM + n] = f2b(acc[nt][r] + bb);
            }
        }
    }
}

// ---------------- K5: weighted combine ----------------
template<int MODE>
__global__ __launch_bounds__(256) void combine_kernel(
    const u32* __restrict__ flag,
    const u16* __restrict__ y_packed, const u32* __restrict__ offsets,
    const u32* __restrict__ tok_e, const u32* __restrict__ tok_pos,
    const float* __restrict__ tok_w, void* __restrict__ out)
{
    if (*flag != (u32)MODE) return;
    const int t = blockIdx.x;
    const u32 e0 = tok_e[t * 2], e1 = tok_e[t * 2 + 1];
    const u32 p0 = offsets[e0] + tok_pos[t * 2];
    const u32 p1 = offsets[e1] + tok_pos[t * 2 + 1];
    const float w0 = tok_w[t * 2], w1 = tok_w[t * 2 + 1];
    const u16* y0 = y_packed + (size_t)p0 * DDIM;
    const u16* y1 = y_packed + (size_t)p1 * DDIM;
    for (int c = threadIdx.x; c < DDIM; c += 256) {
        const float v = w0 * b2f(y0[c]) + w1 * b2f(y1[c]);
        if (MODE == 0) ((u16*)out)[(size_t)t * DDIM + c] = f2b(v);
        else           ((float*)out)[(size_t)t * DDIM + c] = v;
    }
}

extern "C" void kernel_launch(void* const* d_in, const int* in_sizes, int n_in,
                              void* d_out, int out_size, void* d_ws, size_t ws_size,
                              hipStream_t stream)
{
    const void* x     = d_in[0];
    const void* rw    = d_in[1];
    const void* rb    = d_in[2];
    const void* fc1_w = d_in[3];
    const void* fc1_b = d_in[4];
    const void* fc2_w = d_in[5];
    const void* fc2_b = d_in[6];

    char* ws = (char*)d_ws;
    size_t off = 0;
    auto take = [&](size_t bytes) -> char* {
        char* p = ws + off;
        off = (off + bytes + 255) & ~(size_t)255;
        return p;
    };
    u32* flag     = (u32*)take(4);
    u32* counts   = (u32*)take(NEXP * 4);
    u32* offsets  = (u32*)take(NEXP * 4);
    u16* list     = (u16*)take((size_t)NEXP * NTOK * 2);
    u32* tok_e    = (u32*)take((size_t)NTOK * 2 * 4);
    u32* tok_pos  = (u32*)take((size_t)NTOK * 2 * 4);
    float* tok_w  = (float*)take((size_t)NTOK * 2 * 4);
    u16* a_packed = (u16*)take((size_t)2 * NTOK * HDIM * 2);   // 16 MB
    u16* y_pack   = (u16*)take((size_t)2 * NTOK * DDIM * 2);   // 8 MB
    (void)ws_size; (void)in_sizes; (void)n_in; (void)out_size;

    detect_kernel<<<1, 64, 0, stream>>>((const u16*)x, flag, counts);

    router_kernel<0><<<NTOK / 4, 256, 0, stream>>>(flag, x, rw, rb, counts, list, tok_e, tok_pos, tok_w);
    router_kernel<1><<<NTOK / 4, 256, 0, stream>>>(flag, x, rw, rb, counts, list, tok_e, tok_pos, tok_w);

    prefix_kernel<<<1, 64, 0, stream>>>(counts, offsets);

    const dim3 g1(HDIM / 64, NTOK / 64, NEXP);
    fc1_swiglu_kernel<0><<<g1, 256, 0, stream>>>(flag, x, fc1_w, fc1_b, counts, offsets, list, a_packed);
    fc1_swiglu_kernel<1><<<g1, 256, 0, stream>>>(flag, x, fc1_w, fc1_b, counts, offsets, list, a_packed);

    const dim3 g2(DDIM / 64, NTOK / 64, NEXP);
    fc2_kernel<0><<<g2, 256, 0, stream>>>(flag, a_packed, fc2_w, fc2_b, counts, offsets, y_pack);
    fc2_kernel<1><<<g2, 256, 0, stream>>>(flag, a_packed, fc2_w, fc2_b, counts, offsets, y_pack);

    combine_kernel<0><<<NTOK, 256, 0, stream>>>(flag, y_pack, offsets, tok_e, tok_pos, tok_w, d_out);
    combine_kernel<1><<<NTOK, 256, 0, stream>>>(flag, y_pack, offsets, tok_e, tok_pos, tok_w, d_out);
}

// Round 5
// 319.011 us; speedup vs baseline: 1.0003x; 1.0003x over previous
//
#include <hip/hip_runtime.h>

typedef unsigned int u32;
typedef unsigned short u16;
typedef unsigned long long u64;

#define NTOK 4096
#define DDIM 512
#define NEXP 8
#define HDIM 1024

typedef __attribute__((ext_vector_type(8))) __bf16 bf16x8;
typedef __attribute__((ext_vector_type(4))) float f32x4;

__device__ __forceinline__ float b2f(u16 u) {
    union { u32 i; float f; } v; v.i = ((u32)u) << 16; return v.f;
}
__device__ __forceinline__ u16 f2b(float f) {
    u32 x = __builtin_bit_cast(u32, f);
    x += 0x7fffu + ((x >> 16) & 1u);
    return (u16)(x >> 16);
}

// MODE 0 = tensors are bf16 in memory; MODE 1 = tensors are f32 in memory.
template<int MODE>
__device__ __forceinline__ float ldf(const void* p, size_t i) {
    return MODE ? ((const float*)p)[i] : b2f(((const u16*)p)[i]);
}

// Load 16 consecutive elements (element index `elem`, multiple of 16) as 16 bf16
// packed into two uint4.
template<int MODE>
__device__ __forceinline__ void load16(const void* base, size_t elem, uint4& lo, uint4& hi) {
    if (MODE == 0) {
        const uint4* p = (const uint4*)((const u16*)base + elem);
        lo = p[0]; hi = p[1];
    } else {
        const float4* p = (const float4*)((const float*)base + elem);
        const float4 a = p[0], b = p[1], c = p[2], d = p[3];
        union { u16 t[16]; uint4 v[2]; } u;
        u.t[0] = f2b(a.x); u.t[1] = f2b(a.y); u.t[2]  = f2b(a.z); u.t[3]  = f2b(a.w);
        u.t[4] = f2b(b.x); u.t[5] = f2b(b.y); u.t[6]  = f2b(b.z); u.t[7]  = f2b(b.w);
        u.t[8] = f2b(c.x); u.t[9] = f2b(c.y); u.t[10] = f2b(c.z); u.t[11] = f2b(c.w);
        u.t[12] = f2b(d.x); u.t[13] = f2b(d.y); u.t[14] = f2b(d.z); u.t[15] = f2b(d.w);
        lo = u.v[0]; hi = u.v[1];
    }
}

// ---------------- K0: detect dtype + zero expert counts ----------------
// Even-indexed u16s of x: bf16 -> sane exponents (~100%); f32 low-halves -> ~17%.
__global__ void detect_kernel(const u16* __restrict__ x, u32* __restrict__ flag,
                              u32* __restrict__ counts) {
    const int lane = threadIdx.x & 63;
    const u16 v = x[lane * 2];
    const int ex = (v >> 7) & 0xFF;
    const bool ok = (ex >= 97 && ex <= 140);   // |val| in [2^-30, 2^14]
    const u64 m = __ballot(ok);
    if (threadIdx.x == 0) *flag = (__popcll(m) >= 32) ? 0u : 1u;
    if (threadIdx.x < NEXP) counts[threadIdx.x] = 0;
}

// ---------------- K1: router (one wave per token) ----------------
template<int MODE>
__global__ __launch_bounds__(256) void router_kernel(
    const u32* __restrict__ flag,
    const void* __restrict__ x, const void* __restrict__ rw, const void* __restrict__ rb,
    u32* __restrict__ counts, u16* __restrict__ list,
    u32* __restrict__ tok_e, u32* __restrict__ tok_pos, float* __restrict__ tok_w)
{
    if (*flag != (u32)MODE) return;
    const int tid = threadIdx.x;
    const int lane = tid & 63;
    const int t = blockIdx.x * 4 + (tid >> 6);

    float xf[8];
    if (MODE == 0) {
        const uint4 xv = ((const uint4*)((const u16*)x + (size_t)t * DDIM))[lane];
        const u16* xs = (const u16*)&xv;
#pragma unroll
        for (int i = 0; i < 8; i++) xf[i] = b2f(xs[i]);
    } else {
        const float4* p = (const float4*)((const float*)x + (size_t)t * DDIM + lane * 8);
        const float4 a = p[0], b = p[1];
        xf[0] = a.x; xf[1] = a.y; xf[2] = a.z; xf[3] = a.w;
        xf[4] = b.x; xf[5] = b.y; xf[6] = b.z; xf[7] = b.w;
    }

    float acc[NEXP];
#pragma unroll
    for (int e = 0; e < NEXP; e++) {
        float wf[8];
        if (MODE == 0) {
            const uint4 wv = ((const uint4*)((const u16*)rw + e * DDIM))[lane];
            const u16* wp = (const u16*)&wv;
#pragma unroll
            for (int i = 0; i < 8; i++) wf[i] = b2f(wp[i]);
        } else {
            const float4* p = (const float4*)((const float*)rw + e * DDIM + lane * 8);
            const float4 a = p[0], b = p[1];
            wf[0] = a.x; wf[1] = a.y; wf[2] = a.z; wf[3] = a.w;
            wf[4] = b.x; wf[5] = b.y; wf[6] = b.z; wf[7] = b.w;
        }
        float s = 0.f;
#pragma unroll
        for (int i = 0; i < 8; i++) s += xf[i] * wf[i];
        acc[e] = s;
    }
#pragma unroll
    for (int off = 32; off > 0; off >>= 1) {
#pragma unroll
        for (int e = 0; e < NEXP; e++) acc[e] += __shfl_xor(acc[e], off, 64);
    }
    if (lane == 0) {
#pragma unroll
        for (int e = 0; e < NEXP; e++) acc[e] += ldf<MODE>(rb, e);
        int e0 = 0;
#pragma unroll
        for (int e = 1; e < NEXP; e++) if (acc[e] > acc[e0]) e0 = e;
        int e1 = -1;
#pragma unroll
        for (int e = 0; e < NEXP; e++) {
            if (e == e0) continue;
            if (e1 < 0 || acc[e] > acc[e1]) e1 = e;
        }
        const float v0 = acc[e0], v1 = acc[e1];
        const float w1v = 1.f / (1.f + __expf(v0 - v1));
        const float w0v = 1.f - w1v;
        const u32 p0 = atomicAdd(&counts[e0], 1u);
        const u32 p1 = atomicAdd(&counts[e1], 1u);
        list[e0 * NTOK + p0] = (u16)t;
        list[e1 * NTOK + p1] = (u16)t;
        tok_e[t * 2] = (u32)e0;      tok_pos[t * 2] = p0;      tok_w[t * 2] = w0v;
        tok_e[t * 2 + 1] = (u32)e1;  tok_pos[t * 2 + 1] = p1;  tok_w[t * 2 + 1] = w1v;
    }
}

// ---------------- K2: exclusive prefix over 8 counts ----------------
__global__ void prefix_kernel(const u32* __restrict__ counts, u32* __restrict__ offsets) {
    if (threadIdx.x == 0) {
        u32 o = 0;
        for (int e = 0; e < NEXP; e++) { offsets[e] = o; o += counts[e]; }
    }
}

// ---------------- K3: gathered fc1 + SwiGLU (bf16 MFMA 16x16x32) ----------------
template<int MODE>
__global__ __launch_bounds__(256) void fc1_swiglu_kernel(
    const u32* __restrict__ flag,
    const void* __restrict__ x, const void* __restrict__ fc1_w, const void* __restrict__ fc1_b,
    const u32* __restrict__ counts, const u32* __restrict__ offsets,
    const u16* __restrict__ list, u16* __restrict__ a_packed)
{
    if (*flag != (u32)MODE) return;
    const int e = blockIdx.z;
    const int cnt = (int)counts[e];
    const int row0 = blockIdx.y * 64;
    if (row0 >= cnt) return;
    const int n0 = blockIdx.x * 64;

    __shared__ u16 As[64 * 64], B1s[64 * 64], B2s[64 * 64];

    const int tid = threadIdx.x;
    const int lr = tid >> 2;            // loader row 0..63
    const int lc = (tid & 3) * 16;      // loader col base (elements)
    int ar = row0 + lr; if (ar >= cnt) ar = cnt - 1;
    const int tok = (int)list[e * NTOK + ar];
    const size_t a_base  = (size_t)tok * DDIM;
    const size_t b1_base = ((size_t)e * 2 * HDIM + (size_t)(n0 + lr)) * DDIM;
    const size_t b2_base = ((size_t)e * 2 * HDIM + (size_t)(n0 + HDIM + lr)) * DDIM;

    const int sw = lr & 7;
    const int c0 = lc >> 3;
    u16* as0  = &As[lr * 64 + ((c0 ^ sw) << 3)];
    u16* as1  = &As[lr * 64 + (((c0 + 1) ^ sw) << 3)];
    u16* b1s0 = &B1s[lr * 64 + ((c0 ^ sw) << 3)];
    u16* b1s1 = &B1s[lr * 64 + (((c0 + 1) ^ sw) << 3)];
    u16* b2s0 = &B2s[lr * 64 + ((c0 ^ sw) << 3)];
    u16* b2s1 = &B2s[lr * 64 + (((c0 + 1) ^ sw) << 3)];

    const int wave = tid >> 6, lane = tid & 63;
    const int mm = lane & 15;
    const int qb = lane >> 4;
    const int msw = mm & 7;
    const u16* a_rd = &As[(wave * 16 + mm) * 64];

    f32x4 acc1[4] = {f32x4{0,0,0,0},f32x4{0,0,0,0},f32x4{0,0,0,0},f32x4{0,0,0,0}};
    f32x4 acc2[4] = {f32x4{0,0,0,0},f32x4{0,0,0,0},f32x4{0,0,0,0},f32x4{0,0,0,0}};

    for (int k0 = 0; k0 < DDIM; k0 += 64) {
        uint4 av0, av1, b10, b11, b20, b21;
        load16<MODE>(x,     a_base  + k0 + lc, av0, av1);
        load16<MODE>(fc1_w, b1_base + k0 + lc, b10, b11);
        load16<MODE>(fc1_w, b2_base + k0 + lc, b20, b21);
        __syncthreads();
        *(uint4*)as0  = av0; *(uint4*)as1  = av1;
        *(uint4*)b1s0 = b10; *(uint4*)b1s1 = b11;
        *(uint4*)b2s0 = b20; *(uint4*)b2s1 = b21;
        __syncthreads();
#pragma unroll
        for (int kk = 0; kk < 2; kk++) {
            const int q = kk * 4 + qb;
            const bf16x8 af = *(const bf16x8*)(a_rd + ((q ^ msw) << 3));
#pragma unroll
            for (int nt = 0; nt < 4; nt++) {
                const bf16x8 bf1 = *(const bf16x8*)(&B1s[(nt * 16 + mm) * 64 + ((q ^ msw) << 3)]);
                const bf16x8 bf2 = *(const bf16x8*)(&B2s[(nt * 16 + mm) * 64 + ((q ^ msw) << 3)]);
                acc1[nt] = __builtin_amdgcn_mfma_f32_16x16x32_bf16(af, bf1, acc1[nt], 0, 0, 0);
                acc2[nt] = __builtin_amdgcn_mfma_f32_16x16x32_bf16(af, bf2, acc2[nt], 0, 0, 0);
            }
        }
    }

    const u32 obase = offsets[e];
    const int rbv = (lane >> 4) * 4;
#pragma unroll
    for (int nt = 0; nt < 4; nt++) {
        const int n = n0 + nt * 16 + mm;
        const float bb1 = ldf<MODE>(fc1_b, (size_t)e * 2 * HDIM + n);
        const float bb2 = ldf<MODE>(fc1_b, (size_t)e * 2 * HDIM + HDIM + n);
#pragma unroll
        for (int r = 0; r < 4; r++) {
            const int gr = row0 + wave * 16 + rbv + r;
            if (gr < cnt) {
                const float h1 = acc1[nt][r] + bb1;
                const float h2 = acc2[nt][r] + bb2;
                const float av = h1 / (1.f + __expf(-h1)) * h2;
                a_packed[(size_t)(obase + (u32)gr) * HDIM + n] = f2b(av);
            }
        }
    }
}

// ---------------- K4: fc2 on packed rows (bf16 MFMA) ----------------
template<int MODE>
__global__ __launch_bounds__(256) void fc2_kernel(
    const u32* __restrict__ flag,
    const u16* __restrict__ a_packed, const void* __restrict__ fc2_w, const void* __restrict__ fc2_b,
    const u32* __restrict__ counts, const u32* __restrict__ offsets,
    u16* __restrict__ y_packed)
{
    if (*flag != (u32)MODE) return;
    const int e = blockIdx.z;
    const int cnt = (int)counts[e];
    const int row0 = blockIdx.y * 64;
    if (row0 >= cnt) return;
    const int d0 = blockIdx.x * 64;

    __shared__ u16 As[64 * 64], Bs[64 * 64];

    const int tid = threadIdx.x;
    const int lr = tid >> 2;
    const int lc = (tid & 3) * 16;
    const u32 obase = offsets[e];
    int ar = row0 + lr; if (ar >= cnt) ar = cnt - 1;
    const size_t a_base = (size_t)(obase + (u32)ar) * HDIM;
    const size_t b_base = ((size_t)e * DDIM + (size_t)(d0 + lr)) * HDIM;

    const int sw = lr & 7;
    const int c0 = lc >> 3;
    u16* as0 = &As[lr * 64 + ((c0 ^ sw) << 3)];
    u16* as1 = &As[lr * 64 + (((c0 + 1) ^ sw) << 3)];
    u16* bs0 = &Bs[lr * 64 + ((c0 ^ sw) << 3)];
    u16* bs1 = &Bs[lr * 64 + (((c0 + 1) ^ sw) << 3)];

    const int wave = tid >> 6, lane = tid & 63;
    const int mm = lane & 15;
    const int qb = lane >> 4;
    const int msw = mm & 7;
    const u16* a_rd = &As[(wave * 16 + mm) * 64];

    f32x4 acc[4] = {f32x4{0,0,0,0},f32x4{0,0,0,0},f32x4{0,0,0,0},f32x4{0,0,0,0}};

    for (int k0 = 0; k0 < HDIM; k0 += 64) {
        uint4 av0, av1, bv0, bv1;
        load16<0>(a_packed, a_base + k0 + lc, av0, av1);       // a is always bf16
        load16<MODE>(fc2_w, b_base + k0 + lc, bv0, bv1);
        __syncthreads();
        *(uint4*)as0 = av0; *(uint4*)as1 = av1;
        *(uint4*)bs0 = bv0; *(uint4*)bs1 = bv1;
        __syncthreads();
#pragma unroll
        for (int kk = 0; kk < 2; kk++) {
            const int q = kk * 4 + qb;
            const bf16x8 af = *(const bf16x8*)(a_rd + ((q ^ msw) << 3));
#pragma unroll
            for (int nt = 0; nt < 4; nt++) {
                const bf16x8 bfv = *(const bf16x8*)(&Bs[(nt * 16 + mm) * 64 + ((q ^ msw) << 3)]);
                acc[nt] = __builtin_amdgcn_mfma_f32_16x16x32_bf16(af, bfv, acc[nt], 0, 0, 0);
            }
        }
    }

    const int rbv = (lane >> 4) * 4;
#pragma unroll
    for (int nt = 0; nt < 4; nt++) {
        const int n = d0 + nt * 16 + mm;
        const float bb = ldf<MODE>(fc2_b, (size_t)e * DDIM + n);
#pragma unroll
        for (int r = 0; r < 4; r++) {
            const int gr = row0 + wave * 16 + rbv + r;
            if (gr < cnt) {
                y_packed[(size_t)(obase + (u32)gr) * DDIM + n] = f2b(acc[nt][r] + bb);
            }
        }
    }
}

// ---------------- K5: weighted combine ----------------
template<int MODE>
__global__ __launch_bounds__(256) void combine_kernel(
    const u32* __restrict__ flag,
    const u16* __restrict__ y_packed, const u32* __restrict__ offsets,
    const u32* __restrict__ tok_e, const u32* __restrict__ tok_pos,
    const float* __restrict__ tok_w, void* __restrict__ out)
{
    if (*flag != (u32)MODE) return;
    const int t = blockIdx.x;
    const u32 e0 = tok_e[t * 2], e1 = tok_e[t * 2 + 1];
    const u32 p0 = offsets[e0] + tok_pos[t * 2];
    const u32 p1 = offsets[e1] + tok_pos[t * 2 + 1];
    const float w0 = tok_w[t * 2], w1 = tok_w[t * 2 + 1];
    const u16* y0 = y_packed + (size_t)p0 * DDIM;
    const u16* y1 = y_packed + (size_t)p1 * DDIM;
    for (int c = threadIdx.x; c < DDIM; c += 256) {
        const float v = w0 * b2f(y0[c]) + w1 * b2f(y1[c]);
        if (MODE == 0) ((u16*)out)[(size_t)t * DDIM + c] = f2b(v);
        else           ((float*)out)[(size_t)t * DDIM + c] = v;
    }
}

extern "C" void kernel_launch(void* const* d_in, const int* in_sizes, int n_in,
                              void* d_out, int out_size, void* d_ws, size_t ws_size,
                              hipStream_t stream)
{
    const void* x     = d_in[0];
    const void* rw    = d_in[1];
    const void* rb    = d_in[2];
    const void* fc1_w = d_in[3];
    const void* fc1_b = d_in[4];
    const void* fc2_w = d_in[5];
    const void* fc2_b = d_in[6];

    char* ws = (char*)d_ws;
    size_t off = 0;
    auto take = [&](size_t bytes) -> char* {
        char* p = ws + off;
        off = (off + bytes + 255) & ~(size_t)255;
        return p;
    };
    u32* flag     = (u32*)take(4);
    u32* counts   = (u32*)take(NEXP * 4);
    u32* offsets  = (u32*)take(NEXP * 4);
    u16* list     = (u16*)take((size_t)NEXP * NTOK * 2);
    u32* tok_e    = (u32*)take((size_t)NTOK * 2 * 4);
    u32* tok_pos  = (u32*)take((size_t)NTOK * 2 * 4);
    float* tok_w  = (float*)take((size_t)NTOK * 2 * 4);
    u16* a_packed = (u16*)take((size_t)2 * NTOK * HDIM * 2);   // 16 MB
    u16* y_pack   = (u16*)take((size_t)2 * NTOK * DDIM * 2);   // 8 MB
    (void)ws_size; (void)in_sizes; (void)n_in; (void)out_size;

    detect_kernel<<<1, 64, 0, stream>>>((const u16*)x, flag, counts);

    router_kernel<0><<<NTOK / 4, 256, 0, stream>>>(flag, x, rw, rb, counts, list, tok_e, tok_pos, tok_w);
    router_kernel<1><<<NTOK / 4, 256, 0, stream>>>(flag, x, rw, rb, counts, list, tok_e, tok_pos, tok_w);

    prefix_kernel<<<1, 64, 0, stream>>>(counts, offsets);

    const dim3 g1(HDIM / 64, NTOK / 64, NEXP);
    fc1_swiglu_kernel<0><<<g1, 256, 0, stream>>>(flag, x, fc1_w, fc1_b, counts, offsets, list, a_packed);
    fc1_swiglu_kernel<1><<<g1, 256, 0, stream>>>(flag, x, fc1_w, fc1_b, counts, offsets, list, a_packed);

    const dim3 g2(DDIM / 64, NTOK / 64, NEXP);
    fc2_kernel<0><<<g2, 256, 0, stream>>>(flag, a_packed, fc2_w, fc2_b, counts, offsets, y_pack);
    fc2_kernel<1><<<g2, 256, 0, stream>>>(flag, a_packed, fc2_w, fc2_b, counts, offsets, y_pack);

    combine_kernel<0><<<NTOK, 256, 0, stream>>>(flag, y_pack, offsets, tok_e, tok_pos, tok_w, d_out);
    combine_kernel<1><<<NTOK, 256, 0, stream>>>(flag, y_pack, offsets, tok_e, tok_pos, tok_w, d_out);
}

// Round 6
// 265.776 us; speedup vs baseline: 1.2007x; 1.2003x over previous
//
#include <hip/hip_runtime.h>

typedef unsigned int u32;
typedef unsigned short u16;
typedef unsigned long long u64;

#define NTOK 4096
#define DDIM 512
#define NEXP 8
#define HDIM 1024

typedef __attribute__((ext_vector_type(8))) __bf16 bf16x8;
typedef __attribute__((ext_vector_type(4))) float f32x4;

__device__ __forceinline__ float b2f(u16 u) {
    union { u32 i; float f; } v; v.i = ((u32)u) << 16; return v.f;
}
__device__ __forceinline__ u16 f2b(float f) {
    u32 x = __builtin_bit_cast(u32, f);
    x += 0x7fffu + ((x >> 16) & 1u);
    return (u16)(x >> 16);
}

// MODE 0 = tensors are bf16 in memory; MODE 1 = tensors are f32 in memory.
template<int MODE>
__device__ __forceinline__ float ldf(const void* p, size_t i) {
    return MODE ? ((const float*)p)[i] : b2f(((const u16*)p)[i]);
}

// Load 16 consecutive elements (element index `elem`, multiple of 16) as 16 bf16
// packed into two uint4.
template<int MODE>
__device__ __forceinline__ void load16(const void* base, size_t elem, uint4& lo, uint4& hi) {
    if (MODE == 0) {
        const uint4* p = (const uint4*)((const u16*)base + elem);
        lo = p[0]; hi = p[1];
    } else {
        const float4* p = (const float4*)((const float*)base + elem);
        const float4 a = p[0], b = p[1], c = p[2], d = p[3];
        union { u16 t[16]; uint4 v[2]; } u;
        u.t[0] = f2b(a.x); u.t[1] = f2b(a.y); u.t[2]  = f2b(a.z); u.t[3]  = f2b(a.w);
        u.t[4] = f2b(b.x); u.t[5] = f2b(b.y); u.t[6]  = f2b(b.z); u.t[7]  = f2b(b.w);
        u.t[8] = f2b(c.x); u.t[9] = f2b(c.y); u.t[10] = f2b(c.z); u.t[11] = f2b(c.w);
        u.t[12] = f2b(d.x); u.t[13] = f2b(d.y); u.t[14] = f2b(d.z); u.t[15] = f2b(d.w);
        lo = u.v[0]; hi = u.v[1];
    }
}

// ---------------- K0: detect dtype + zero expert counts ----------------
// Even-indexed u16s of x: bf16 -> sane exponents (~100%); f32 low-halves -> ~17%.
__global__ void detect_kernel(const u16* __restrict__ x, u32* __restrict__ flag,
                              u32* __restrict__ counts) {
    const int lane = threadIdx.x & 63;
    const u16 v = x[lane * 2];
    const int ex = (v >> 7) & 0xFF;
    const bool ok = (ex >= 97 && ex <= 140);   // |val| in [2^-30, 2^14]
    const u64 m = __ballot(ok);
    if (threadIdx.x == 0) *flag = (__popcll(m) >= 32) ? 0u : 1u;
    if (threadIdx.x < NEXP) counts[threadIdx.x] = 0;
}

// ---------------- K1: router (64 tokens/block, LDS-aggregated atomics) ----------------
// 4 waves x 16 tokens; per-block slot ranks via LDS atomics; only 8 global
// atomicAdds per block (512 total vs 8192 single-token version = the 100us fix).
template<int MODE>
__global__ __launch_bounds__(256) void router_kernel(
    const u32* __restrict__ flag,
    const void* __restrict__ x, const void* __restrict__ rw, const void* __restrict__ rb,
    u32* __restrict__ counts, u16* __restrict__ list,
    u32* __restrict__ tok_e, u32* __restrict__ tok_pos, float* __restrict__ tok_w)
{
    if (*flag != (u32)MODE) return;
    __shared__ u32 bcount[NEXP];   // block-local expert counts
    __shared__ u32 bbase[NEXP];    // reserved global base per expert
    __shared__ u32 srank[128];     // per-slot rank within block
    __shared__ u16 sexp[128];      // per-slot expert id

    const int tid = threadIdx.x;
    const int lane = tid & 63;
    const int wave = tid >> 6;
    if (tid < NEXP) bcount[tid] = 0;

    // preload router weights into registers (wave-invariant across tokens)
    float wreg[NEXP][8];
#pragma unroll
    for (int e = 0; e < NEXP; e++) {
        if (MODE == 0) {
            const uint4 wv = ((const uint4*)((const u16*)rw + e * DDIM))[lane];
            const u16* wp = (const u16*)&wv;
#pragma unroll
            for (int i = 0; i < 8; i++) wreg[e][i] = b2f(wp[i]);
        } else {
            const float4* p = (const float4*)((const float*)rw + e * DDIM + lane * 8);
            const float4 a = p[0], b = p[1];
            wreg[e][0] = a.x; wreg[e][1] = a.y; wreg[e][2] = a.z; wreg[e][3] = a.w;
            wreg[e][4] = b.x; wreg[e][5] = b.y; wreg[e][6] = b.z; wreg[e][7] = b.w;
        }
    }
    float bias[NEXP];
#pragma unroll
    for (int e = 0; e < NEXP; e++) bias[e] = ldf<MODE>(rb, e);

    __syncthreads();   // bcount zeroed before any LDS atomic below

    const int t0 = blockIdx.x * 64;
    for (int tk = 0; tk < 16; tk++) {
        const int lt = wave * 16 + tk;
        const int t = t0 + lt;
        float xf[8];
        if (MODE == 0) {
            const uint4 xv = ((const uint4*)((const u16*)x + (size_t)t * DDIM))[lane];
            const u16* xs = (const u16*)&xv;
#pragma unroll
            for (int i = 0; i < 8; i++) xf[i] = b2f(xs[i]);
        } else {
            const float4* p = (const float4*)((const float*)x + (size_t)t * DDIM + lane * 8);
            const float4 a = p[0], b = p[1];
            xf[0] = a.x; xf[1] = a.y; xf[2] = a.z; xf[3] = a.w;
            xf[4] = b.x; xf[5] = b.y; xf[6] = b.z; xf[7] = b.w;
        }
        float acc[NEXP];
#pragma unroll
        for (int e = 0; e < NEXP; e++) {
            float s = 0.f;
#pragma unroll
            for (int i = 0; i < 8; i++) s += xf[i] * wreg[e][i];
            acc[e] = s;
        }
#pragma unroll
        for (int off = 32; off > 0; off >>= 1) {
#pragma unroll
            for (int e = 0; e < NEXP; e++) acc[e] += __shfl_xor(acc[e], off, 64);
        }
        if (lane == 0) {
#pragma unroll
            for (int e = 0; e < NEXP; e++) acc[e] += bias[e];
            // top-2, lowest-index tie-break (matches lax.top_k)
            int e0 = 0;
#pragma unroll
            for (int e = 1; e < NEXP; e++) if (acc[e] > acc[e0]) e0 = e;
            int e1 = -1;
#pragma unroll
            for (int e = 0; e < NEXP; e++) {
                if (e == e0) continue;
                if (e1 < 0 || acc[e] > acc[e1]) e1 = e;
            }
            const float w1v = 1.f / (1.f + __expf(acc[e0] - acc[e1]));
            tok_e[t * 2] = (u32)e0;      tok_w[t * 2] = 1.f - w1v;
            tok_e[t * 2 + 1] = (u32)e1;  tok_w[t * 2 + 1] = w1v;
            sexp[lt * 2] = (u16)e0;
            sexp[lt * 2 + 1] = (u16)e1;
            srank[lt * 2]     = atomicAdd(&bcount[e0], 1u);
            srank[lt * 2 + 1] = atomicAdd(&bcount[e1], 1u);
        }
    }
    __syncthreads();
    if (tid < NEXP) bbase[tid] = atomicAdd(&counts[tid], bcount[tid]);
    __syncthreads();
    if (tid < 128) {
        const int s = tid;
        const int lt = s >> 1;
        const int t = t0 + lt;
        const u32 e = (u32)sexp[s];
        const u32 pos = bbase[e] + srank[s];
        list[e * NTOK + pos] = (u16)t;
        tok_pos[t * 2 + (s & 1)] = pos;
    }
}

// ---------------- K2: exclusive prefix over 8 counts ----------------
__global__ void prefix_kernel(const u32* __restrict__ counts, u32* __restrict__ offsets) {
    if (threadIdx.x == 0) {
        u32 o = 0;
        for (int e = 0; e < NEXP; e++) { offsets[e] = o; o += counts[e]; }
    }
}

// ---------------- K3: gathered fc1 + SwiGLU (bf16 MFMA 16x16x32) ----------------
template<int MODE>
__global__ __launch_bounds__(256) void fc1_swiglu_kernel(
    const u32* __restrict__ flag,
    const void* __restrict__ x, const void* __restrict__ fc1_w, const void* __restrict__ fc1_b,
    const u32* __restrict__ counts, const u32* __restrict__ offsets,
    const u16* __restrict__ list, u16* __restrict__ a_packed)
{
    if (*flag != (u32)MODE) return;
    const int e = blockIdx.z;
    const int cnt = (int)counts[e];
    const int row0 = blockIdx.y * 64;
    if (row0 >= cnt) return;
    const int n0 = blockIdx.x * 64;

    __shared__ u16 As[64 * 64], B1s[64 * 64], B2s[64 * 64];

    const int tid = threadIdx.x;
    const int lr = tid >> 2;            // loader row 0..63
    const int lc = (tid & 3) * 16;      // loader col base (elements)
    int ar = row0 + lr; if (ar >= cnt) ar = cnt - 1;
    const int tok = min((int)list[e * NTOK + ar], NTOK - 1);   // clamp: corruption -> finite, not NaN
    const size_t a_base  = (size_t)tok * DDIM;
    const size_t b1_base = ((size_t)e * 2 * HDIM + (size_t)(n0 + lr)) * DDIM;
    const size_t b2_base = ((size_t)e * 2 * HDIM + (size_t)(n0 + HDIM + lr)) * DDIM;

    const int sw = lr & 7;
    const int c0 = lc >> 3;
    u16* as0  = &As[lr * 64 + ((c0 ^ sw) << 3)];
    u16* as1  = &As[lr * 64 + (((c0 + 1) ^ sw) << 3)];
    u16* b1s0 = &B1s[lr * 64 + ((c0 ^ sw) << 3)];
    u16* b1s1 = &B1s[lr * 64 + (((c0 + 1) ^ sw) << 3)];
    u16* b2s0 = &B2s[lr * 64 + ((c0 ^ sw) << 3)];
    u16* b2s1 = &B2s[lr * 64 + (((c0 + 1) ^ sw) << 3)];

    const int wave = tid >> 6, lane = tid & 63;
    const int mm = lane & 15;
    const int qb = lane >> 4;
    const int msw = mm & 7;
    const u16* a_rd = &As[(wave * 16 + mm) * 64];

    f32x4 acc1[4] = {f32x4{0,0,0,0},f32x4{0,0,0,0},f32x4{0,0,0,0},f32x4{0,0,0,0}};
    f32x4 acc2[4] = {f32x4{0,0,0,0},f32x4{0,0,0,0},f32x4{0,0,0,0},f32x4{0,0,0,0}};

    for (int k0 = 0; k0 < DDIM; k0 += 64) {
        uint4 av0, av1, b10, b11, b20, b21;
        load16<MODE>(x,     a_base  + k0 + lc, av0, av1);
        load16<MODE>(fc1_w, b1_base + k0 + lc, b10, b11);
        load16<MODE>(fc1_w, b2_base + k0 + lc, b20, b21);
        __syncthreads();
        *(uint4*)as0  = av0; *(uint4*)as1  = av1;
        *(uint4*)b1s0 = b10; *(uint4*)b1s1 = b11;
        *(uint4*)b2s0 = b20; *(uint4*)b2s1 = b21;
        __syncthreads();
#pragma unroll
        for (int kk = 0; kk < 2; kk++) {
            const int q = kk * 4 + qb;
            const bf16x8 af = *(const bf16x8*)(a_rd + ((q ^ msw) << 3));
#pragma unroll
            for (int nt = 0; nt < 4; nt++) {
                const bf16x8 bf1 = *(const bf16x8*)(&B1s[(nt * 16 + mm) * 64 + ((q ^ msw) << 3)]);
                const bf16x8 bf2 = *(const bf16x8*)(&B2s[(nt * 16 + mm) * 64 + ((q ^ msw) << 3)]);
                acc1[nt] = __builtin_amdgcn_mfma_f32_16x16x32_bf16(af, bf1, acc1[nt], 0, 0, 0);
                acc2[nt] = __builtin_amdgcn_mfma_f32_16x16x32_bf16(af, bf2, acc2[nt], 0, 0, 0);
            }
        }
    }

    const u32 obase = offsets[e];
    const int rbv = (lane >> 4) * 4;
#pragma unroll
    for (int nt = 0; nt < 4; nt++) {
        const int n = n0 + nt * 16 + mm;
        const float bb1 = ldf<MODE>(fc1_b, (size_t)e * 2 * HDIM + n);
        const float bb2 = ldf<MODE>(fc1_b, (size_t)e * 2 * HDIM + HDIM + n);
#pragma unroll
        for (int r = 0; r < 4; r++) {
            const int gr = row0 + wave * 16 + rbv + r;
            if (gr < cnt) {
                const float h1 = acc1[nt][r] + bb1;
                const float h2 = acc2[nt][r] + bb2;
                const float av = h1 / (1.f + __expf(-h1)) * h2;
                a_packed[(size_t)(obase + (u32)gr) * HDIM + n] = f2b(av);
            }
        }
    }
}

// ---------------- K4: fc2 on packed rows (bf16 MFMA) ----------------
template<int MODE>
__global__ __launch_bounds__(256) void fc2_kernel(
    const u32* __restrict__ flag,
    const u16* __restrict__ a_packed, const void* __restrict__ fc2_w, const void* __restrict__ fc2_b,
    const u32* __restrict__ counts, const u32* __restrict__ offsets,
    u16* __restrict__ y_packed)
{
    if (*flag != (u32)MODE) return;
    const int e = blockIdx.z;
    const int cnt = (int)counts[e];
    const int row0 = blockIdx.y * 64;
    if (row0 >= cnt) return;
    const int d0 = blockIdx.x * 64;

    __shared__ u16 As[64 * 64], Bs[64 * 64];

    const int tid = threadIdx.x;
    const int lr = tid >> 2;
    const int lc = (tid & 3) * 16;
    const u32 obase = offsets[e];
    int ar = row0 + lr; if (ar >= cnt) ar = cnt - 1;
    const size_t a_base = (size_t)(obase + (u32)ar) * HDIM;
    const size_t b_base = ((size_t)e * DDIM + (size_t)(d0 + lr)) * HDIM;

    const int sw = lr & 7;
    const int c0 = lc >> 3;
    u16* as0 = &As[lr * 64 + ((c0 ^ sw) << 3)];
    u16* as1 = &As[lr * 64 + (((c0 + 1) ^ sw) << 3)];
    u16* bs0 = &Bs[lr * 64 + ((c0 ^ sw) << 3)];
    u16* bs1 = &Bs[lr * 64 + (((c0 + 1) ^ sw) << 3)];

    const int wave = tid >> 6, lane = tid & 63;
    const int mm = lane & 15;
    const int qb = lane >> 4;
    const int msw = mm & 7;
    const u16* a_rd = &As[(wave * 16 + mm) * 64];

    f32x4 acc[4] = {f32x4{0,0,0,0},f32x4{0,0,0,0},f32x4{0,0,0,0},f32x4{0,0,0,0}};

    for (int k0 = 0; k0 < HDIM; k0 += 64) {
        uint4 av0, av1, bv0, bv1;
        load16<0>(a_packed, a_base + k0 + lc, av0, av1);       // a is always bf16
        load16<MODE>(fc2_w, b_base + k0 + lc, bv0, bv1);
        __syncthreads();
        *(uint4*)as0 = av0; *(uint4*)as1 = av1;
        *(uint4*)bs0 = bv0; *(uint4*)bs1 = bv1;
        __syncthreads();
#pragma unroll
        for (int kk = 0; kk < 2; kk++) {
            const int q = kk * 4 + qb;
            const bf16x8 af = *(const bf16x8*)(a_rd + ((q ^ msw) << 3));
#pragma unroll
            for (int nt = 0; nt < 4; nt++) {
                const bf16x8 bfv = *(const bf16x8*)(&Bs[(nt * 16 + mm) * 64 + ((q ^ msw) << 3)]);
                acc[nt] = __builtin_amdgcn_mfma_f32_16x16x32_bf16(af, bfv, acc[nt], 0, 0, 0);
            }
        }
    }

    const int rbv = (lane >> 4) * 4;
#pragma unroll
    for (int nt = 0; nt < 4; nt++) {
        const int n = d0 + nt * 16 + mm;
        const float bb = ldf<MODE>(fc2_b, (size_t)e * DDIM + n);
#pragma unroll
        for (int r = 0; r < 4; r++) {
            const int gr = row0 + wave * 16 + rbv + r;
            if (gr < cnt) {
                y_packed[(size_t)(obase + (u32)gr) * DDIM + n] = f2b(acc[nt][r] + bb);
            }
        }
    }
}

// ---------------- K5: weighted combine ----------------
template<int MODE>
__global__ __launch_bounds__(256) void combine_kernel(
    const u32* __restrict__ flag,
    const u16* __restrict__ y_packed, const u32* __restrict__ offsets,
    const u32* __restrict__ tok_e, const u32* __restrict__ tok_pos,
    const float* __restrict__ tok_w, void* __restrict__ out)
{
    if (*flag != (u32)MODE) return;
    const int t = blockIdx.x;
    const u32 e0 = tok_e[t * 2] & 7u, e1 = tok_e[t * 2 + 1] & 7u;
    const u32 p0 = min(offsets[e0] + tok_pos[t * 2], (u32)(2 * NTOK - 1));      // clamp: corruption -> finite
    const u32 p1 = min(offsets[e1] + tok_pos[t * 2 + 1], (u32)(2 * NTOK - 1));
    const float w0 = tok_w[t * 2], w1 = tok_w[t * 2 + 1];
    const u16* y0 = y_packed + (size_t)p0 * DDIM;
    const u16* y1 = y_packed + (size_t)p1 * DDIM;
    for (int c = threadIdx.x; c < DDIM; c += 256) {
        const float v = w0 * b2f(y0[c]) + w1 * b2f(y1[c]);
        if (MODE == 0) ((u16*)out)[(size_t)t * DDIM + c] = f2b(v);
        else           ((float*)out)[(size_t)t * DDIM + c] = v;
    }
}

extern "C" void kernel_launch(void* const* d_in, const int* in_sizes, int n_in,
                              void* d_out, int out_size, void* d_ws, size_t ws_size,
                              hipStream_t stream)
{
    const void* x     = d_in[0];
    const void* rw    = d_in[1];
    const void* rb    = d_in[2];
    const void* fc1_w = d_in[3];
    const void* fc1_b = d_in[4];
    const void* fc2_w = d_in[5];
    const void* fc2_b = d_in[6];

    char* ws = (char*)d_ws;
    size_t off = 0;
    auto take = [&](size_t bytes) -> char* {
        char* p = ws + off;
        off = (off + bytes + 255) & ~(size_t)255;
        return p;
    };
    u32* flag     = (u32*)take(4);
    u32* counts   = (u32*)take(NEXP * 4);
    u32* offsets  = (u32*)take(NEXP * 4);
    u16* list     = (u16*)take((size_t)NEXP * NTOK * 2);
    u32* tok_e    = (u32*)take((size_t)NTOK * 2 * 4);
    u32* tok_pos  = (u32*)take((size_t)NTOK * 2 * 4);
    float* tok_w  = (float*)take((size_t)NTOK * 2 * 4);
    u16* a_packed = (u16*)take((size_t)2 * NTOK * HDIM * 2);   // 16 MB
    u16* y_pack   = (u16*)take((size_t)2 * NTOK * DDIM * 2);   // 8 MB
    (void)ws_size; (void)in_sizes; (void)n_in; (void)out_size;

    detect_kernel<<<1, 64, 0, stream>>>((const u16*)x, flag, counts);

    router_kernel<0><<<NTOK / 64, 256, 0, stream>>>(flag, x, rw, rb, counts, list, tok_e, tok_pos, tok_w);
    router_kernel<1><<<NTOK / 64, 256, 0, stream>>>(flag, x, rw, rb, counts, list, tok_e, tok_pos, tok_w);

    prefix_kernel<<<1, 64, 0, stream>>>(counts, offsets);

    const dim3 g1(HDIM / 64, NTOK / 64, NEXP);
    fc1_swiglu_kernel<0><<<g1, 256, 0, stream>>>(flag, x, fc1_w, fc1_b, counts, offsets, list, a_packed);
    fc1_swiglu_kernel<1><<<g1, 256, 0, stream>>>(flag, x, fc1_w, fc1_b, counts, offsets, list, a_packed);

    const dim3 g2(DDIM / 64, NTOK / 64, NEXP);
    fc2_kernel<0><<<g2, 256, 0, stream>>>(flag, a_packed, fc2_w, fc2_b, counts, offsets, y_pack);
    fc2_kernel<1><<<g2, 256, 0, stream>>>(flag, a_packed, fc2_w, fc2_b, counts, offsets, y_pack);

    combine_kernel<0><<<NTOK, 256, 0, stream>>>(flag, y_pack, offsets, tok_e, tok_pos, tok_w, d_out);
    combine_kernel<1><<<NTOK, 256, 0, stream>>>(flag, y_pack, offsets, tok_e, tok_pos, tok_w, d_out);
}

// Round 7
// 255.992 us; speedup vs baseline: 1.2466x; 1.0382x over previous
//
#include <hip/hip_runtime.h>

typedef unsigned int u32;
typedef unsigned short u16;
typedef unsigned long long u64;

#define NTOK 4096
#define DDIM 512
#define NEXP 8
#define HDIM 1024

typedef __attribute__((ext_vector_type(8))) __bf16 bf16x8;
typedef __attribute__((ext_vector_type(4))) float f32x4;

__device__ __forceinline__ float b2f(u16 u) {
    union { u32 i; float f; } v; v.i = ((u32)u) << 16; return v.f;
}
__device__ __forceinline__ u16 f2b(float f) {
    u32 x = __builtin_bit_cast(u32, f);
    x += 0x7fffu + ((x >> 16) & 1u);
    return (u16)(x >> 16);
}

// MODE 0 = tensors are bf16 in memory; MODE 1 = tensors are f32 in memory.
template<int MODE>
__device__ __forceinline__ float ldf(const void* p, size_t i) {
    return MODE ? ((const float*)p)[i] : b2f(((const u16*)p)[i]);
}

// Load 16 consecutive elements (element index `elem`, multiple of 16) as 16 bf16
// packed into two uint4.
template<int MODE>
__device__ __forceinline__ void load16(const void* base, size_t elem, uint4& lo, uint4& hi) {
    if (MODE == 0) {
        const uint4* p = (const uint4*)((const u16*)base + elem);
        lo = p[0]; hi = p[1];
    } else {
        const float4* p = (const float4*)((const float*)base + elem);
        const float4 a = p[0], b = p[1], c = p[2], d = p[3];
        union { u16 t[16]; uint4 v[2]; } u;
        u.t[0] = f2b(a.x); u.t[1] = f2b(a.y); u.t[2]  = f2b(a.z); u.t[3]  = f2b(a.w);
        u.t[4] = f2b(b.x); u.t[5] = f2b(b.y); u.t[6]  = f2b(b.z); u.t[7]  = f2b(b.w);
        u.t[8] = f2b(c.x); u.t[9] = f2b(c.y); u.t[10] = f2b(c.z); u.t[11] = f2b(c.w);
        u.t[12] = f2b(d.x); u.t[13] = f2b(d.y); u.t[14] = f2b(d.z); u.t[15] = f2b(d.w);
        lo = u.v[0]; hi = u.v[1];
    }
}

// ---------------- K0: detect dtype + zero expert counts ----------------
__global__ void detect_kernel(const u16* __restrict__ x, u32* __restrict__ flag,
                              u32* __restrict__ counts) {
    const int lane = threadIdx.x & 63;
    const u16 v = x[lane * 2];
    const int ex = (v >> 7) & 0xFF;
    const bool ok = (ex >= 97 && ex <= 140);   // |val| in [2^-30, 2^14]
    const u64 m = __ballot(ok);
    if (threadIdx.x == 0) *flag = (__popcll(m) >= 32) ? 0u : 1u;
    if (threadIdx.x < NEXP) counts[threadIdx.x] = 0;
}

// ---------------- K1: router (64 tokens/block, LDS-aggregated atomics) ----------------
template<int MODE>
__global__ __launch_bounds__(256) void router_kernel(
    const u32* __restrict__ flag,
    const void* __restrict__ x, const void* __restrict__ rw, const void* __restrict__ rb,
    u32* __restrict__ counts, u16* __restrict__ list,
    u32* __restrict__ tok_e, u32* __restrict__ tok_pos, float* __restrict__ tok_w)
{
    if (*flag != (u32)MODE) return;
    __shared__ u32 bcount[NEXP];
    __shared__ u32 bbase[NEXP];
    __shared__ u32 srank[128];
    __shared__ u16 sexp[128];

    const int tid = threadIdx.x;
    const int lane = tid & 63;
    const int wave = tid >> 6;
    if (tid < NEXP) bcount[tid] = 0;

    float wreg[NEXP][8];
#pragma unroll
    for (int e = 0; e < NEXP; e++) {
        if (MODE == 0) {
            const uint4 wv = ((const uint4*)((const u16*)rw + e * DDIM))[lane];
            const u16* wp = (const u16*)&wv;
#pragma unroll
            for (int i = 0; i < 8; i++) wreg[e][i] = b2f(wp[i]);
        } else {
            const float4* p = (const float4*)((const float*)rw + e * DDIM + lane * 8);
            const float4 a = p[0], b = p[1];
            wreg[e][0] = a.x; wreg[e][1] = a.y; wreg[e][2] = a.z; wreg[e][3] = a.w;
            wreg[e][4] = b.x; wreg[e][5] = b.y; wreg[e][6] = b.z; wreg[e][7] = b.w;
        }
    }
    float bias[NEXP];
#pragma unroll
    for (int e = 0; e < NEXP; e++) bias[e] = ldf<MODE>(rb, e);

    __syncthreads();

    const int t0 = blockIdx.x * 64;
    for (int tk = 0; tk < 16; tk++) {
        const int lt = wave * 16 + tk;
        const int t = t0 + lt;
        float xf[8];
        if (MODE == 0) {
            const uint4 xv = ((const uint4*)((const u16*)x + (size_t)t * DDIM))[lane];
            const u16* xs = (const u16*)&xv;
#pragma unroll
            for (int i = 0; i < 8; i++) xf[i] = b2f(xs[i]);
        } else {
            const float4* p = (const float4*)((const float*)x + (size_t)t * DDIM + lane * 8);
            const float4 a = p[0], b = p[1];
            xf[0] = a.x; xf[1] = a.y; xf[2] = a.z; xf[3] = a.w;
            xf[4] = b.x; xf[5] = b.y; xf[6] = b.z; xf[7] = b.w;
        }
        float acc[NEXP];
#pragma unroll
        for (int e = 0; e < NEXP; e++) {
            float s = 0.f;
#pragma unroll
            for (int i = 0; i < 8; i++) s += xf[i] * wreg[e][i];
            acc[e] = s;
        }
#pragma unroll
        for (int off = 32; off > 0; off >>= 1) {
#pragma unroll
            for (int e = 0; e < NEXP; e++) acc[e] += __shfl_xor(acc[e], off, 64);
        }
        if (lane == 0) {
#pragma unroll
            for (int e = 0; e < NEXP; e++) acc[e] += bias[e];
            int e0 = 0;
#pragma unroll
            for (int e = 1; e < NEXP; e++) if (acc[e] > acc[e0]) e0 = e;
            int e1 = -1;
#pragma unroll
            for (int e = 0; e < NEXP; e++) {
                if (e == e0) continue;
                if (e1 < 0 || acc[e] > acc[e1]) e1 = e;
            }
            const float w1v = 1.f / (1.f + __expf(acc[e0] - acc[e1]));
            tok_e[t * 2] = (u32)e0;      tok_w[t * 2] = 1.f - w1v;
            tok_e[t * 2 + 1] = (u32)e1;  tok_w[t * 2 + 1] = w1v;
            sexp[lt * 2] = (u16)e0;
            sexp[lt * 2 + 1] = (u16)e1;
            srank[lt * 2]     = atomicAdd(&bcount[e0], 1u);
            srank[lt * 2 + 1] = atomicAdd(&bcount[e1], 1u);
        }
    }
    __syncthreads();
    if (tid < NEXP) bbase[tid] = atomicAdd(&counts[tid], bcount[tid]);
    __syncthreads();
    if (tid < 128) {
        const int s = tid;
        const int lt = s >> 1;
        const int t = t0 + lt;
        const u32 e = (u32)sexp[s];
        const u32 pos = bbase[e] + srank[s];
        list[e * NTOK + pos] = (u16)t;
        tok_pos[t * 2 + (s & 1)] = pos;
    }
}

// ---------------- K2: exclusive prefix over 8 counts ----------------
__global__ void prefix_kernel(const u32* __restrict__ counts, u32* __restrict__ offsets) {
    if (threadIdx.x == 0) {
        u32 o = 0;
        for (int e = 0; e < NEXP; e++) { offsets[e] = o; o += counts[e]; }
    }
}

// ---------------- K3: gathered fc1 + SwiGLU, 128x64 tile, prefetched ----------------
// Block: 128 gathered rows x 64 a-cols. Wave: 64 rows x 32 cols x {h1,h2}.
// Per K-step/wave: 16 ds_read_b128 vs 32 MFMA (2x the old ratio); next K-step's
// global loads issue before the MFMA section (latency hidden under compute).
template<int MODE>
__global__ __launch_bounds__(256, 3) void fc1_swiglu_kernel(
    const u32* __restrict__ flag,
    const void* __restrict__ x, const void* __restrict__ fc1_w, const void* __restrict__ fc1_b,
    const u32* __restrict__ counts, const u32* __restrict__ offsets,
    const u16* __restrict__ list, u16* __restrict__ a_packed)
{
    if (*flag != (u32)MODE) return;
    const int e = blockIdx.z;
    const int cnt = (int)counts[e];
    const int row0 = blockIdx.y * 128;
    if (row0 >= cnt) return;
    const int n0 = blockIdx.x * 64;

    __shared__ u16 As[128 * 64], B1s[64 * 64], B2s[64 * 64];

    const int tid = threadIdx.x;
    const int lr = tid >> 2;        // 0..63: A rows lr & lr+64; B rows lr
    const int lcc = tid & 3;        // 16-elem chunk within row
    const int lc = lcc * 16;

    int ar0 = row0 + lr;       if (ar0 >= cnt) ar0 = cnt - 1;
    int ar1 = row0 + 64 + lr;  if (ar1 >= cnt) ar1 = cnt - 1;
    const int tok0 = min((int)list[e * NTOK + ar0], NTOK - 1);
    const int tok1 = min((int)list[e * NTOK + ar1], NTOK - 1);
    const size_t a_base0 = (size_t)tok0 * DDIM;
    const size_t a_base1 = (size_t)tok1 * DDIM;
    const size_t b1_base = ((size_t)e * 2 * HDIM + (size_t)(n0 + lr)) * DDIM;
    const size_t b2_base = ((size_t)e * 2 * HDIM + (size_t)(n0 + HDIM + lr)) * DDIM;

    const int sw = lr & 7;          // (lr+64)&7 == lr&7
    const int c0 = lcc * 2;
    u16* as0a = &As[lr * 64 + ((c0 ^ sw) << 3)];
    u16* as0b = &As[lr * 64 + (((c0 + 1) ^ sw) << 3)];
    u16* as1a = &As[(lr + 64) * 64 + ((c0 ^ sw) << 3)];
    u16* as1b = &As[(lr + 64) * 64 + (((c0 + 1) ^ sw) << 3)];
    u16* b1a  = &B1s[lr * 64 + ((c0 ^ sw) << 3)];
    u16* b1b  = &B1s[lr * 64 + (((c0 + 1) ^ sw) << 3)];
    u16* b2a  = &B2s[lr * 64 + ((c0 ^ sw) << 3)];
    u16* b2b  = &B2s[lr * 64 + (((c0 + 1) ^ sw) << 3)];

    const int wave = tid >> 6, lane = tid & 63;
    const int mrow0 = (wave >> 1) * 64;   // wave row base within 128
    const int ncol0 = (wave & 1) * 32;    // wave col base within 64
    const int mm = lane & 15;
    const int qb = lane >> 4;
    const int msw = mm & 7;

    f32x4 acc1[4][2], acc2[4][2];
#pragma unroll
    for (int mt = 0; mt < 4; mt++)
#pragma unroll
        for (int nt = 0; nt < 2; nt++) {
            acc1[mt][nt] = f32x4{0, 0, 0, 0};
            acc2[mt][nt] = f32x4{0, 0, 0, 0};
        }

    uint4 A0l, A0h, A1l, A1h, B1l, B1h, B2l, B2h;
    load16<MODE>(x,     a_base0 + lc, A0l, A0h);
    load16<MODE>(x,     a_base1 + lc, A1l, A1h);
    load16<MODE>(fc1_w, b1_base + lc, B1l, B1h);
    load16<MODE>(fc1_w, b2_base + lc, B2l, B2h);

    for (int k0 = 0; k0 < DDIM; k0 += 64) {
        __syncthreads();
        *(uint4*)as0a = A0l; *(uint4*)as0b = A0h;
        *(uint4*)as1a = A1l; *(uint4*)as1b = A1h;
        *(uint4*)b1a  = B1l; *(uint4*)b1b  = B1h;
        *(uint4*)b2a  = B2l; *(uint4*)b2b  = B2h;
        __syncthreads();
        if (k0 + 64 < DDIM) {
            load16<MODE>(x,     a_base0 + k0 + 64 + lc, A0l, A0h);
            load16<MODE>(x,     a_base1 + k0 + 64 + lc, A1l, A1h);
            load16<MODE>(fc1_w, b1_base + k0 + 64 + lc, B1l, B1h);
            load16<MODE>(fc1_w, b2_base + k0 + 64 + lc, B2l, B2h);
        }
#pragma unroll
        for (int kk = 0; kk < 2; kk++) {
            const int g = kk * 4 + qb;
            bf16x8 af[4];
#pragma unroll
            for (int mt = 0; mt < 4; mt++)
                af[mt] = *(const bf16x8*)(&As[(mrow0 + mt * 16 + mm) * 64 + ((g ^ msw) << 3)]);
#pragma unroll
            for (int nt = 0; nt < 2; nt++) {
                const bf16x8 b1f = *(const bf16x8*)(&B1s[(ncol0 + nt * 16 + mm) * 64 + ((g ^ msw) << 3)]);
                const bf16x8 b2f = *(const bf16x8*)(&B2s[(ncol0 + nt * 16 + mm) * 64 + ((g ^ msw) << 3)]);
#pragma unroll
                for (int mt = 0; mt < 4; mt++) {
                    acc1[mt][nt] = __builtin_amdgcn_mfma_f32_16x16x32_bf16(af[mt], b1f, acc1[mt][nt], 0, 0, 0);
                    acc2[mt][nt] = __builtin_amdgcn_mfma_f32_16x16x32_bf16(af[mt], b2f, acc2[mt][nt], 0, 0, 0);
                }
            }
        }
    }

    const u32 obase = offsets[e];
    const int rbv = qb * 4;
#pragma unroll
    for (int nt = 0; nt < 2; nt++) {
        const int n = n0 + ncol0 + nt * 16 + mm;
        const float bb1 = ldf<MODE>(fc1_b, (size_t)e * 2 * HDIM + n);
        const float bb2 = ldf<MODE>(fc1_b, (size_t)e * 2 * HDIM + HDIM + n);
#pragma unroll
        for (int mt = 0; mt < 4; mt++) {
#pragma unroll
            for (int r = 0; r < 4; r++) {
                const int gr = row0 + mrow0 + mt * 16 + rbv + r;
                if (gr < cnt) {
                    const float h1 = acc1[mt][nt][r] + bb1;
                    const float h2 = acc2[mt][nt][r] + bb2;
                    const float av = h1 / (1.f + __expf(-h1)) * h2;
                    a_packed[(size_t)(obase + (u32)gr) * HDIM + n] = f2b(av);
                }
            }
        }
    }
}

// ---------------- K4: fc2, 128x64 tile, prefetched ----------------
template<int MODE>
__global__ __launch_bounds__(256, 3) void fc2_kernel(
    const u32* __restrict__ flag,
    const u16* __restrict__ a_packed, const void* __restrict__ fc2_w, const void* __restrict__ fc2_b,
    const u32* __restrict__ counts, const u32* __restrict__ offsets,
    u16* __restrict__ y_packed)
{
    if (*flag != (u32)MODE) return;
    const int e = blockIdx.z;
    const int cnt = (int)counts[e];
    const int row0 = blockIdx.y * 128;
    if (row0 >= cnt) return;
    const int d0 = blockIdx.x * 64;

    __shared__ u16 As[128 * 64], Bs[64 * 64];

    const int tid = threadIdx.x;
    const int lr = tid >> 2;
    const int lcc = tid & 3;
    const int lc = lcc * 16;
    const u32 obase = offsets[e];

    int ar0 = row0 + lr;       if (ar0 >= cnt) ar0 = cnt - 1;
    int ar1 = row0 + 64 + lr;  if (ar1 >= cnt) ar1 = cnt - 1;
    const size_t a_base0 = (size_t)(obase + (u32)ar0) * HDIM;
    const size_t a_base1 = (size_t)(obase + (u32)ar1) * HDIM;
    const size_t b_base  = ((size_t)e * DDIM + (size_t)(d0 + lr)) * HDIM;

    const int sw = lr & 7;
    const int c0 = lcc * 2;
    u16* as0a = &As[lr * 64 + ((c0 ^ sw) << 3)];
    u16* as0b = &As[lr * 64 + (((c0 + 1) ^ sw) << 3)];
    u16* as1a = &As[(lr + 64) * 64 + ((c0 ^ sw) << 3)];
    u16* as1b = &As[(lr + 64) * 64 + (((c0 + 1) ^ sw) << 3)];
    u16* bsa  = &Bs[lr * 64 + ((c0 ^ sw) << 3)];
    u16* bsb  = &Bs[lr * 64 + (((c0 + 1) ^ sw) << 3)];

    const int wave = tid >> 6, lane = tid & 63;
    const int mrow0 = (wave >> 1) * 64;
    const int ncol0 = (wave & 1) * 32;
    const int mm = lane & 15;
    const int qb = lane >> 4;
    const int msw = mm & 7;

    f32x4 acc[4][2];
#pragma unroll
    for (int mt = 0; mt < 4; mt++)
#pragma unroll
        for (int nt = 0; nt < 2; nt++) acc[mt][nt] = f32x4{0, 0, 0, 0};

    uint4 A0l, A0h, A1l, A1h, Bl, Bh;
    load16<0>(a_packed, a_base0 + lc, A0l, A0h);
    load16<0>(a_packed, a_base1 + lc, A1l, A1h);
    load16<MODE>(fc2_w, b_base + lc, Bl, Bh);

    for (int k0 = 0; k0 < HDIM; k0 += 64) {
        __syncthreads();
        *(uint4*)as0a = A0l; *(uint4*)as0b = A0h;
        *(uint4*)as1a = A1l; *(uint4*)as1b = A1h;
        *(uint4*)bsa  = Bl;  *(uint4*)bsb  = Bh;
        __syncthreads();
        if (k0 + 64 < HDIM) {
            load16<0>(a_packed, a_base0 + k0 + 64 + lc, A0l, A0h);
            load16<0>(a_packed, a_base1 + k0 + 64 + lc, A1l, A1h);
            load16<MODE>(fc2_w, b_base + k0 + 64 + lc, Bl, Bh);
        }
#pragma unroll
        for (int kk = 0; kk < 2; kk++) {
            const int g = kk * 4 + qb;
            bf16x8 af[4];
#pragma unroll
            for (int mt = 0; mt < 4; mt++)
                af[mt] = *(const bf16x8*)(&As[(mrow0 + mt * 16 + mm) * 64 + ((g ^ msw) << 3)]);
#pragma unroll
            for (int nt = 0; nt < 2; nt++) {
                const bf16x8 bfv = *(const bf16x8*)(&Bs[(ncol0 + nt * 16 + mm) * 64 + ((g ^ msw) << 3)]);
#pragma unroll
                for (int mt = 0; mt < 4; mt++)
                    acc[mt][nt] = __builtin_amdgcn_mfma_f32_16x16x32_bf16(af[mt], bfv, acc[mt][nt], 0, 0, 0);
            }
        }
    }

    const int rbv = qb * 4;
#pragma unroll
    for (int nt = 0; nt < 2; nt++) {
        const int n = d0 + ncol0 + nt * 16 + mm;
        const float bb = ldf<MODE>(fc2_b, (size_t)e * DDIM + n);
#pragma unroll
        for (int mt = 0; mt < 4; mt++) {
#pragma unroll
            for (int r = 0; r < 4; r++) {
                const int gr = row0 + mrow0 + mt * 16 + rbv + r;
                if (gr < cnt) {
                    y_packed[(size_t)(obase + (u32)gr) * DDIM + n] = f2b(acc[mt][nt][r] + bb);
                }
            }
        }
    }
}

// ---------------- K5: weighted combine ----------------
template<int MODE>
__global__ __launch_bounds__(256) void combine_kernel(
    const u32* __restrict__ flag,
    const u16* __restrict__ y_packed, const u32* __restrict__ offsets,
    const u32* __restrict__ tok_e, const u32* __restrict__ tok_pos,
    const float* __restrict__ tok_w, void* __restrict__ out)
{
    if (*flag != (u32)MODE) return;
    const int t = blockIdx.x;
    const u32 e0 = tok_e[t * 2] & 7u, e1 = tok_e[t * 2 + 1] & 7u;
    const u32 p0 = min(offsets[e0] + tok_pos[t * 2], (u32)(2 * NTOK - 1));
    const u32 p1 = min(offsets[e1] + tok_pos[t * 2 + 1], (u32)(2 * NTOK - 1));
    const float w0 = tok_w[t * 2], w1 = tok_w[t * 2 + 1];
    const u16* y0 = y_packed + (size_t)p0 * DDIM;
    const u16* y1 = y_packed + (size_t)p1 * DDIM;
    for (int c = threadIdx.x; c < DDIM; c += 256) {
        const float v = w0 * b2f(y0[c]) + w1 * b2f(y1[c]);
        if (MODE == 0) ((u16*)out)[(size_t)t * DDIM + c] = f2b(v);
        else           ((float*)out)[(size_t)t * DDIM + c] = v;
    }
}

extern "C" void kernel_launch(void* const* d_in, const int* in_sizes, int n_in,
                              void* d_out, int out_size, void* d_ws, size_t ws_size,
                              hipStream_t stream)
{
    const void* x     = d_in[0];
    const void* rw    = d_in[1];
    const void* rb    = d_in[2];
    const void* fc1_w = d_in[3];
    const void* fc1_b = d_in[4];
    const void* fc2_w = d_in[5];
    const void* fc2_b = d_in[6];

    char* ws = (char*)d_ws;
    size_t off = 0;
    auto take = [&](size_t bytes) -> char* {
        char* p = ws + off;
        off = (off + bytes + 255) & ~(size_t)255;
        return p;
    };
    u32* flag     = (u32*)take(4);
    u32* counts   = (u32*)take(NEXP * 4);
    u32* offsets  = (u32*)take(NEXP * 4);
    u16* list     = (u16*)take((size_t)NEXP * NTOK * 2);
    u32* tok_e    = (u32*)take((size_t)NTOK * 2 * 4);
    u32* tok_pos  = (u32*)take((size_t)NTOK * 2 * 4);
    float* tok_w  = (float*)take((size_t)NTOK * 2 * 4);
    u16* a_packed = (u16*)take((size_t)2 * NTOK * HDIM * 2);   // 16 MB
    u16* y_pack   = (u16*)take((size_t)2 * NTOK * DDIM * 2);   // 8 MB
    (void)ws_size; (void)in_sizes; (void)n_in; (void)out_size;

    detect_kernel<<<1, 64, 0, stream>>>((const u16*)x, flag, counts);

    router_kernel<0><<<NTOK / 64, 256, 0, stream>>>(flag, x, rw, rb, counts, list, tok_e, tok_pos, tok_w);
    router_kernel<1><<<NTOK / 64, 256, 0, stream>>>(flag, x, rw, rb, counts, list, tok_e, tok_pos, tok_w);

    prefix_kernel<<<1, 64, 0, stream>>>(counts, offsets);

    const dim3 g1(HDIM / 64, NTOK / 128, NEXP);
    fc1_swiglu_kernel<0><<<g1, 256, 0, stream>>>(flag, x, fc1_w, fc1_b, counts, offsets, list, a_packed);
    fc1_swiglu_kernel<1><<<g1, 256, 0, stream>>>(flag, x, fc1_w, fc1_b, counts, offsets, list, a_packed);

    const dim3 g2(DDIM / 64, NTOK / 128, NEXP);
    fc2_kernel<0><<<g2, 256, 0, stream>>>(flag, a_packed, fc2_w, fc2_b, counts, offsets, y_pack);
    fc2_kernel<1><<<g2, 256, 0, stream>>>(flag, a_packed, fc2_w, fc2_b, counts, offsets, y_pack);

    combine_kernel<0><<<NTOK, 256, 0, stream>>>(flag, y_pack, offsets, tok_e, tok_pos, tok_w, d_out);
    combine_kernel<1><<<NTOK, 256, 0, stream>>>(flag, y_pack, offsets, tok_e, tok_pos, tok_w, d_out);
}